// Round 8
// baseline (172.886 us; speedup 1.0000x reference)
//
#include <hip/hip_runtime.h>
#include <hip/hip_bf16.h>
#include <stdint.h>
#include <math.h>

#define B_ 2
#define T_ 2048
#define C_ 1024
#define H_ 16
#define HD_ 64
#define BT_ (B_*T_)      // 4096 rows
#define N1_ (3*C_)       // 3072

typedef unsigned short u16;
typedef uint32_t u32;
typedef __attribute__((ext_vector_type(8))) short bf16x8;
typedef __attribute__((ext_vector_type(4))) float f32x4;
typedef __attribute__((ext_vector_type(16))) float f32x16;
typedef __attribute__((ext_vector_type(4))) unsigned int u32x4;

__device__ __forceinline__ u16 f2bf(float f) {
  __hip_bfloat16 h = __float2bfloat16(f);
  return *reinterpret_cast<u16*>(&h);
}
__device__ __forceinline__ float bf2f(u16 u) {
  u32 w = ((u32)u) << 16;
  return *reinterpret_cast<float*>(&w);
}

__device__ __forceinline__ void gload_lds16(const void* g, void* l) {
  __builtin_amdgcn_global_load_lds(
      (const __attribute__((address_space(1))) uint32_t*)g,
      (__attribute__((address_space(3))) uint32_t*)l, 16, 0, 0);
}

// ---------------- cast x: fp32 -> bf16 ----------------
__global__ void cast_f32_bf16_k(const float* __restrict__ in, u16* __restrict__ out, int n) {
  int idx = (blockIdx.x * blockDim.x + threadIdx.x) * 4;
  if (idx >= n) return;
  float4 v = *reinterpret_cast<const float4*>(in + idx);
  u16 tmp[4] = {f2bf(v.x), f2bf(v.y), f2bf(v.z), f2bf(v.w)};
  *reinterpret_cast<uint2*>(out + idx) = *reinterpret_cast<const uint2*>(tmp);
}

// ---------------- transpose+cast: w (K x N fp32) -> wt (N x K bf16) ----------------
__global__ void transcast_k(const float* __restrict__ w, u16* __restrict__ wt, int K, int N) {
  __shared__ float tile[32][33];
  int n0 = blockIdx.x * 32, k0 = blockIdx.y * 32;
  int tx = threadIdx.x, ty = threadIdx.y;   // block (32,8)
#pragma unroll
  for (int i = 0; i < 4; i++)
    tile[ty + i*8][tx] = w[(size_t)(k0 + ty + i*8) * N + n0 + tx];
  __syncthreads();
#pragma unroll
  for (int i = 0; i < 4; i++)
    wt[(size_t)(n0 + ty + i*8) * K + k0 + tx] = f2bf(tile[tx][ty + i*8]);
}

// ---------------- GEMM: A (M x K bf16), Bt (N x K bf16) -> C (M x N) ----------------
template<int OUTF32>
__global__ __launch_bounds__(256) void gemm_bt(const u16* __restrict__ A, const u16* __restrict__ Bt,
                                               void* __restrict__ Cv, int M, int N, int K) {
  __shared__ u16 As[128*32];
  __shared__ u16 Bs[128*32];
  int tid = threadIdx.x, wave = tid >> 6, lane = tid & 63;
  int m0 = blockIdx.y * 128, n0 = blockIdx.x * 128;
  int wm = (wave >> 1) * 64, wn = (wave & 1) * 64;
  f32x4 acc[4][4] = {};
  int srow = lane >> 2, scol = (lane & 3) * 8;
  int fro  = (lane & 15) * 32 + (lane >> 4) * 8;

  for (int k0 = 0; k0 < K; k0 += 32) {
    __syncthreads();
#pragma unroll
    for (int i = 0; i < 2; i++) {
      gload_lds16(A  + (size_t)(m0 + i*64 + wave*16 + srow) * K + k0 + scol, &As[(i*64 + wave*16) * 32]);
      gload_lds16(Bt + (size_t)(n0 + i*64 + wave*16 + srow) * K + k0 + scol, &Bs[(i*64 + wave*16) * 32]);
    }
    asm volatile("s_waitcnt vmcnt(0)" ::: "memory");
    __syncthreads();
    bf16x8 af[4], bfr[4];
#pragma unroll
    for (int i = 0; i < 4; i++) af[i]  = *reinterpret_cast<const bf16x8*>(&As[(wm + i*16)*32 + fro]);
#pragma unroll
    for (int j = 0; j < 4; j++) bfr[j] = *reinterpret_cast<const bf16x8*>(&Bs[(wn + j*16)*32 + fro]);
#pragma unroll
    for (int i = 0; i < 4; i++)
#pragma unroll
      for (int j = 0; j < 4; j++)
        acc[i][j] = __builtin_amdgcn_mfma_f32_16x16x32_bf16(af[i], bfr[j], acc[i][j], 0, 0, 0);
  }
  int rg = (lane >> 4) * 4, cq = lane & 15;
#pragma unroll
  for (int i = 0; i < 4; i++)
#pragma unroll
    for (int j = 0; j < 4; j++) {
      size_t basei = (size_t)(m0 + wm + i*16 + rg) * N + (size_t)(n0 + wn + j*16 + cq);
#pragma unroll
      for (int r = 0; r < 4; r++) {
        if constexpr (OUTF32) ((float*)Cv)[basei + (size_t)r * N] = acc[i][j][r];
        else                  ((u16*)Cv)[basei + (size_t)r * N]   = f2bf(acc[i][j][r]);
      }
    }
}

// ---------------- causal flash attention: 1 wave / block, no barriers ----------------
// 2048 single-wave blocks. lid low 6 bits = strip rank, alternating long/short so any
// contiguous scheduler window is mean-balanced; bh = lid>>6.
// K staged via pre-swizzled global_load_lds (R6-proven); V reg-staged -> packed
// ds_write_b32 swizzled transpose (R6-proven). Counted-vmcnt 2-deep pipeline:
// vmcnt(8) before QK (K landed, V-regs in flight); vmcnt(8) before V-write
// (V-regs ready, K(t+1) in flight). vmcnt(0) only on the final tile.
__global__ __launch_bounds__(64) void attn_kernel(const u16* __restrict__ qkv, u16* __restrict__ attnout) {
  __shared__ u16 Ks[64*64];   // (key,d): elem = key*64 + ((d>>3)^(key&7))*8 + (d&7)
  __shared__ u16 Vt[64*64];   // (d,key): elem = d*64 + ((key>>3)^(d&7))*8 + (key&7)
  int lane = threadIdx.x;
  int q31 = lane & 31, hi = lane >> 5;
  int lid = blockIdx.x;
  int r6 = lid & 63;
  int strip = (r6 & 1) ? (r6 >> 1) : 63 - (r6 >> 1);   // pairs (63,0),(1,62),... sum const
  int bh = lid >> 6;
  int b = bh >> 4, h = bh & 15;
  int qbase = strip * 32;
  int qg = qbase + q31;
  const u16* base = qkv + (size_t)b * T_ * N1_;

  // Q fragments pre-scaled by 0.125*log2(e): qf[kk] = Q[qg][16kk+8hi .. +7]
  const float QSC = 0.125f * 1.44269504088896f;
  bf16x8 qf[4];
  {
    const u16* qrow = base + (size_t)qg * N1_ + h * HD_;
#pragma unroll
    for (int kk = 0; kk < 4; kk++) {
      bf16x8 raw = *reinterpret_cast<const bf16x8*>(qrow + kk*16 + hi*8);
      const u16* rp = (const u16*)&raw;
      u32x4 qp;
#pragma unroll
      for (int j = 0; j < 4; j++)
        qp[j] = (u32)f2bf(bf2f(rp[2*j]) * QSC) | ((u32)f2bf(bf2f(rp[2*j+1]) * QSC) << 16);
      qf[kk] = __builtin_bit_cast(bf16x8, qp);
    }
  }

  // K staging source (pre-swizzled): key = 8r + (lane>>3), slot = lane&7 -> c = slot ^ (key&7)
  const u16* ksrc = base + C_ + h*HD_ + (size_t)(lane >> 3) * N1_
                    + (size_t)(((lane & 7) ^ ((lane >> 3) & 7)) * 8);
  // V staging: lane covers keys (2kp, 2kp+1) x d-chunks (hi + 2r)*8
  int kp = q31;
  const u16* vsrc = base + 2*C_ + h*HD_ + (size_t)(2*kp) * N1_ + hi*8;
  u32* Vt32 = reinterpret_cast<u32*>(Vt);

  f32x16 oacc[2] = {};           // O^T: row d = (reg&3)+8(reg>>2)+4hi (+32dt), col q = q31
  float m_run = -__builtin_inff(), l_run = 0.f;
  int nkt = (qbase >> 6) + 1;    // 64-key tiles this strip needs

  bf16x8 vA[4], vB[4];
  // ---- prologue: issue K(0) gloads, then V(0) reg-loads (no drain) ----
#pragma unroll
  for (int r = 0; r < 8; r++)
    gload_lds16(ksrc + (size_t)(8*r) * N1_, (char*)Ks + r*1024);
#pragma unroll
  for (int r = 0; r < 4; r++) {
    vA[r] = *reinterpret_cast<const bf16x8*>(vsrc + r*16);
    vB[r] = *reinterpret_cast<const bf16x8*>(vsrc + r*16 + N1_);
  }

  for (int kt = 0; kt < nkt; kt++) {
    int kb = kt * 64;
    bool last = (kt == nkt - 1);

    // ---- wait K(t) landed (V(t) reg-loads may stay in flight) ----
    asm volatile("s_waitcnt vmcnt(8)" ::: "memory");

    // ---- QK^T: st[ks] = S^T (rows=keys, cols=queries) ----
    f32x16 st[2];
#pragma unroll
    for (int ks = 0; ks < 2; ks++) {
      f32x16 z = {};
#pragma unroll
      for (int kk = 0; kk < 4; kk++) {
        bf16x8 kf = *reinterpret_cast<const bf16x8*>(
            &Ks[(32*ks + q31)*64 + ((((kk<<1) | hi) ^ (q31 & 7)) << 3)]);
        z = __builtin_amdgcn_mfma_f32_32x32x16_bf16(kf, qf[kk], z, 0, 0, 0);
      }
      st[ks] = z;
    }
    asm volatile("s_waitcnt lgkmcnt(0)" ::: "memory");   // Ks reads retired
    __builtin_amdgcn_sched_barrier(0);

    // ---- prefetch K(t+1) into Ks (safe: QK reads drained) ----
    if (!last) {
      size_t off = (size_t)(kb + 64) * N1_;
#pragma unroll
      for (int r = 0; r < 8; r++)
        gload_lds16(ksrc + off + (size_t)(8*r) * N1_, (char*)Ks + r*1024);
    }

    // ---- online softmax (exp2 domain, lane-local q); mask only last tile ----
    float tmax = -__builtin_inff();
    if (last) {
#pragma unroll
      for (int ks = 0; ks < 2; ks++)
#pragma unroll
        for (int r = 0; r < 16; r++) {
          int keyg = kb + 32*ks + (r&3) + 8*(r>>2) + 4*hi;
          float s = (keyg > qg) ? -__builtin_inff() : st[ks][r];
          st[ks][r] = s;
          tmax = fmaxf(tmax, s);
        }
    } else {
#pragma unroll
      for (int ks = 0; ks < 2; ks++)
#pragma unroll
        for (int r = 0; r < 16; r++) tmax = fmaxf(tmax, st[ks][r]);
    }
    tmax = fmaxf(tmax, __shfl_xor(tmax, 32));
    if (!__all(tmax <= m_run + 8.f)) {
      float mnew = fmaxf(m_run, tmax);
      float rs = exp2f(m_run - mnew);
      l_run *= rs;
      m_run = mnew;
#pragma unroll
      for (int dt = 0; dt < 2; dt++)
#pragma unroll
        for (int r = 0; r < 16; r++) oacc[dt][r] *= rs;
    }
    float tsum = 0.f;
#pragma unroll
    for (int ks = 0; ks < 2; ks++)
#pragma unroll
      for (int r = 0; r < 16; r++) {
        float p = exp2f(st[ks][r] - m_run);
        st[ks][r] = p;
        tsum += p;
      }
    l_run += tsum + __shfl_xor(tsum, 32);

    // ---- P pack + half-wave exchange -> pf[kc] (B-frags, keys 16kc+8hi+j) ----
    bf16x8 pf[4];
#pragma unroll
    for (int ks = 0; ks < 2; ks++) {
      u32 pk[8], rc[8];
#pragma unroll
      for (int m = 0; m < 8; m++)
        pk[m] = (u32)f2bf(st[ks][2*m]) | ((u32)f2bf(st[ks][2*m+1]) << 16);
#pragma unroll
      for (int m = 0; m < 8; m++)
        rc[m] = (u32)__shfl_xor((int)pk[m], 32);
      u32x4 fr0 = { hi ? rc[2] : pk[0], hi ? rc[3] : pk[1], hi ? pk[2] : rc[0], hi ? pk[3] : rc[1] };
      u32x4 fr1 = { hi ? rc[6] : pk[4], hi ? rc[7] : pk[5], hi ? pk[6] : rc[4], hi ? pk[7] : rc[5] };
      pf[2*ks]   = __builtin_bit_cast(bf16x8, fr0);
      pf[2*ks+1] = __builtin_bit_cast(bf16x8, fr1);
    }

    // ---- wait V(t) reg-loads ready (K(t+1) may remain in flight) ----
    if (!last) asm volatile("s_waitcnt vmcnt(8)" ::: "memory");
    else       asm volatile("s_waitcnt vmcnt(0)" ::: "memory");

    // ---- transpose-write V(t) into Vt (packed b32, swizzled; R6-proven) ----
#pragma unroll
    for (int r = 0; r < 4; r++) {
      const u16* au = (const u16*)&vA[r];
      const u16* bu = (const u16*)&vB[r];
#pragma unroll
      for (int i = 0; i < 8; i++) {
        int d = (hi + 2*r)*8 + i;
        Vt32[d*32 + (((kp>>2) ^ (d&7)) << 2) + (kp&3)] = (u32)au[i] | ((u32)bu[i] << 16);
      }
    }

    // ---- issue V(t+1) reg-loads (latency hidden under PV + next QK) ----
    if (!last) {
      size_t off = (size_t)(kb + 64) * N1_;
#pragma unroll
      for (int r = 0; r < 4; r++) {
        vA[r] = *reinterpret_cast<const bf16x8*>(vsrc + off + r*16);
        vB[r] = *reinterpret_cast<const bf16x8*>(vsrc + off + r*16 + N1_);
      }
    }

    // ---- PV: O^T += V^T * P^T (compiler handles write->read lgkm deps) ----
#pragma unroll
    for (int dt = 0; dt < 2; dt++)
#pragma unroll
      for (int kc = 0; kc < 4; kc++) {
        int c = (kc << 1) | hi;
        bf16x8 vf = *reinterpret_cast<const bf16x8*>(
            &Vt[(32*dt + q31)*64 + ((c ^ (q31 & 7)) << 3)]);
        oacc[dt] = __builtin_amdgcn_mfma_f32_32x32x16_bf16(vf, pf[kc], oacc[dt], 0, 0, 0);
      }
  }

  // ---- epilogue: divide by l (lane-local), write O (row q = qg) ----
  float linv = 1.f / l_run;
  u16* orow = attnout + (size_t)(b*T_ + qg) * C_ + h*HD_;
#pragma unroll
  for (int dt = 0; dt < 2; dt++)
#pragma unroll
    for (int m = 0; m < 8; m++) {
      int d = 32*dt + 2*(m&1) + 8*(m>>1) + 4*hi;
      u32 v = (u32)f2bf(oacc[dt][2*m] * linv) | ((u32)f2bf(oacc[dt][2*m+1] * linv) << 16);
      *reinterpret_cast<u32*>(orow + d) = v;
    }
}

extern "C" void kernel_launch(void* const* d_in, const int* in_sizes, int n_in,
                              void* d_out, int out_size, void* d_ws, size_t ws_size,
                              hipStream_t stream) {
  const float* x     = (const float*)d_in[0];
  const float* w_qkv = (const float*)d_in[1];
  const float* w_out = (const float*)d_in[2];
  float* out = (float*)d_out;
  char* ws = (char*)d_ws;
  u16* xb    = (u16*)(ws);                         // 8 MB  : x bf16 (4096 x 1024)
  u16* wqkvT = (u16*)(ws + ((size_t)8  << 20));    // 6 MB  : w_qkv^T bf16 (3072 x 1024)
  u16* woutT = (u16*)(ws + ((size_t)14 << 20));    // 2 MB  : w_out^T bf16 (1024 x 1024)
  u16* qkvb  = (u16*)(ws + ((size_t)16 << 20));    // 24 MB : qkv bf16 (4096 x 3072)
  u16* attnb = (u16*)(ws + ((size_t)40 << 20));    // 8 MB  : attn out bf16 (4096 x 1024)

  cast_f32_bf16_k<<<(BT_*C_)/1024, 256, 0, stream>>>(x, xb, BT_*C_);
  transcast_k<<<dim3(N1_/32, C_/32), dim3(32, 8), 0, stream>>>(w_qkv, wqkvT, C_, N1_);
  transcast_k<<<dim3(C_/32, C_/32), dim3(32, 8), 0, stream>>>(w_out, woutT, C_, C_);
  gemm_bt<0><<<dim3(N1_/128, BT_/128), 256, 0, stream>>>(xb, wqkvT, (void*)qkvb, BT_, N1_, C_);
  attn_kernel<<<2048, 64, 0, stream>>>(qkvb, attnb);
  gemm_bt<1><<<dim3(C_/128, BT_/128), 256, 0, stream>>>(attnb, woutT, (void*)out, BT_, C_, C_);
}

// Round 9
// 167.192 us; speedup vs baseline: 1.0341x; 1.0341x over previous
//
#include <hip/hip_runtime.h>
#include <hip/hip_bf16.h>
#include <stdint.h>
#include <math.h>

#define B_ 2
#define T_ 2048
#define C_ 1024
#define H_ 16
#define HD_ 64
#define BT_ (B_*T_)      // 4096 rows
#define N1_ (3*C_)       // 3072

typedef unsigned short u16;
typedef uint32_t u32;
typedef __attribute__((ext_vector_type(8))) short bf16x8;
typedef __attribute__((ext_vector_type(4))) float f32x4;
typedef __attribute__((ext_vector_type(16))) float f32x16;
typedef __attribute__((ext_vector_type(4))) unsigned int u32x4;

__device__ __forceinline__ u16 f2bf(float f) {
  __hip_bfloat16 h = __float2bfloat16(f);
  return *reinterpret_cast<u16*>(&h);
}
__device__ __forceinline__ float bf2f(u16 u) {
  u32 w = ((u32)u) << 16;
  return *reinterpret_cast<float*>(&w);
}

__device__ __forceinline__ void gload_lds16(const void* g, void* l) {
  __builtin_amdgcn_global_load_lds(
      (const __attribute__((address_space(1))) uint32_t*)g,
      (__attribute__((address_space(3))) uint32_t*)l, 16, 0, 0);
}

// ---------------- cast x: fp32 -> bf16 ----------------
__global__ void cast_f32_bf16_k(const float* __restrict__ in, u16* __restrict__ out, int n) {
  int idx = (blockIdx.x * blockDim.x + threadIdx.x) * 4;
  if (idx >= n) return;
  float4 v = *reinterpret_cast<const float4*>(in + idx);
  u16 tmp[4] = {f2bf(v.x), f2bf(v.y), f2bf(v.z), f2bf(v.w)};
  *reinterpret_cast<uint2*>(out + idx) = *reinterpret_cast<const uint2*>(tmp);
}

// ---------------- transpose+cast: w (K x N fp32) -> wt (N x K bf16) ----------------
__global__ void transcast_k(const float* __restrict__ w, u16* __restrict__ wt, int K, int N) {
  __shared__ float tile[32][33];
  int n0 = blockIdx.x * 32, k0 = blockIdx.y * 32;
  int tx = threadIdx.x, ty = threadIdx.y;   // block (32,8)
#pragma unroll
  for (int i = 0; i < 4; i++)
    tile[ty + i*8][tx] = w[(size_t)(k0 + ty + i*8) * N + n0 + tx];
  __syncthreads();
#pragma unroll
  for (int i = 0; i < 4; i++)
    wt[(size_t)(n0 + ty + i*8) * K + k0 + tx] = f2bf(tile[tx][ty + i*8]);
}

// ---------------- GEMM: A (M x K bf16), Bt (N x K bf16) -> C (M x N) ----------------
template<int OUTF32>
__global__ __launch_bounds__(256) void gemm_bt(const u16* __restrict__ A, const u16* __restrict__ Bt,
                                               void* __restrict__ Cv, int M, int N, int K) {
  __shared__ u16 As[128*32];
  __shared__ u16 Bs[128*32];
  int tid = threadIdx.x, wave = tid >> 6, lane = tid & 63;
  int m0 = blockIdx.y * 128, n0 = blockIdx.x * 128;
  int wm = (wave >> 1) * 64, wn = (wave & 1) * 64;
  f32x4 acc[4][4] = {};
  int srow = lane >> 2, scol = (lane & 3) * 8;
  int fro  = (lane & 15) * 32 + (lane >> 4) * 8;

  for (int k0 = 0; k0 < K; k0 += 32) {
    __syncthreads();
#pragma unroll
    for (int i = 0; i < 2; i++) {
      gload_lds16(A  + (size_t)(m0 + i*64 + wave*16 + srow) * K + k0 + scol, &As[(i*64 + wave*16) * 32]);
      gload_lds16(Bt + (size_t)(n0 + i*64 + wave*16 + srow) * K + k0 + scol, &Bs[(i*64 + wave*16) * 32]);
    }
    asm volatile("s_waitcnt vmcnt(0)" ::: "memory");
    __syncthreads();
    bf16x8 af[4], bfr[4];
#pragma unroll
    for (int i = 0; i < 4; i++) af[i]  = *reinterpret_cast<const bf16x8*>(&As[(wm + i*16)*32 + fro]);
#pragma unroll
    for (int j = 0; j < 4; j++) bfr[j] = *reinterpret_cast<const bf16x8*>(&Bs[(wn + j*16)*32 + fro]);
#pragma unroll
    for (int i = 0; i < 4; i++)
#pragma unroll
      for (int j = 0; j < 4; j++)
        acc[i][j] = __builtin_amdgcn_mfma_f32_16x16x32_bf16(af[i], bfr[j], acc[i][j], 0, 0, 0);
  }
  int rg = (lane >> 4) * 4, cq = lane & 15;
#pragma unroll
  for (int i = 0; i < 4; i++)
#pragma unroll
    for (int j = 0; j < 4; j++) {
      size_t basei = (size_t)(m0 + wm + i*16 + rg) * N + (size_t)(n0 + wn + j*16 + cq);
#pragma unroll
      for (int r = 0; r < 4; r++) {
        if constexpr (OUTF32) ((float*)Cv)[basei + (size_t)r * N] = acc[i][j][r];
        else                  ((u16*)Cv)[basei + (size_t)r * N]   = f2bf(acc[i][j][r]);
      }
    }
}

// ---------------- causal flash attention: 1 wave / block, no barriers ----------------
// 1024 single-wave blocks. xcd = lid&7 (matches HW block->XCD round-robin, proven by
// R6's 12MB FETCH): each XCD serves 4 heads -> 2MB K/V L2-resident. Each wave
// processes TWO strips (63-p then p): total tiles = 33 for EVERY wave -> perfect
// static balance under any scheduler assignment. Per-tile body: R8-proven
// counted-vmcnt pipeline (vmcnt(8) waits; vmcnt(0) only on last tile of a strip).
__global__ __launch_bounds__(64) void attn_kernel(const u16* __restrict__ qkv, u16* __restrict__ attnout) {
  __shared__ u16 Ks[64*64];   // (key,d): elem = key*64 + ((d>>3)^(key&7))*8 + (d&7)
  __shared__ u16 Vt[64*64];   // (d,key): elem = d*64 + ((key>>3)^(d&7))*8 + (key&7)
  int lane = threadIdx.x;
  int q31 = lane & 31, hi = lane >> 5;
  int lid = blockIdx.x;
  int xcd = lid & 7, j = lid >> 3;
  int bh = xcd * 4 + (j & 3);          // 4 heads per XCD (L2 locality)
  int p = j >> 2;                      // pair index 0..31 -> strips {63-p, p}
  int b = bh >> 4, h = bh & 15;
  const u16* base = qkv + (size_t)b * T_ * N1_;

  // K staging source (pre-swizzled): key = 8r + (lane>>3), slot = lane&7 -> c = slot ^ (key&7)
  const u16* ksrc = base + C_ + h*HD_ + (size_t)(lane >> 3) * N1_
                    + (size_t)(((lane & 7) ^ ((lane >> 3) & 7)) * 8);
  // V staging: lane covers keys (2kp, 2kp+1) x d-chunks (hi + 2r)*8
  int kp = q31;
  const u16* vsrc = base + 2*C_ + h*HD_ + (size_t)(2*kp) * N1_ + hi*8;
  u32* Vt32 = reinterpret_cast<u32*>(Vt);
  const float QSC = 0.125f * 1.44269504088896f;

  for (int sp = 0; sp < 2; sp++) {
    int strip = sp ? p : (63 - p);     // long strip first, then short
    int qbase = strip * 32;
    int qg = qbase + q31;

    // Q fragments pre-scaled by 0.125*log2(e): qf[kk] = Q[qg][16kk+8hi .. +7]
    bf16x8 qf[4];
    {
      const u16* qrow = base + (size_t)qg * N1_ + h * HD_;
#pragma unroll
      for (int kk = 0; kk < 4; kk++) {
        bf16x8 raw = *reinterpret_cast<const bf16x8*>(qrow + kk*16 + hi*8);
        const u16* rp = (const u16*)&raw;
        u32x4 qp;
#pragma unroll
        for (int jj = 0; jj < 4; jj++)
          qp[jj] = (u32)f2bf(bf2f(rp[2*jj]) * QSC) | ((u32)f2bf(bf2f(rp[2*jj+1]) * QSC) << 16);
        qf[kk] = __builtin_bit_cast(bf16x8, qp);
      }
    }

    f32x16 oacc[2] = {};         // O^T: row d = (reg&3)+8(reg>>2)+4hi (+32dt), col q = q31
    float m_run = -__builtin_inff(), l_run = 0.f;
    int nkt = (qbase >> 6) + 1;  // 64-key tiles this strip needs

    bf16x8 vA[4], vB[4];
    // ---- prologue: issue K(0) gloads, then V(0) reg-loads (no drain) ----
#pragma unroll
    for (int r = 0; r < 8; r++)
      gload_lds16(ksrc + (size_t)(8*r) * N1_, (char*)Ks + r*1024);
#pragma unroll
    for (int r = 0; r < 4; r++) {
      vA[r] = *reinterpret_cast<const bf16x8*>(vsrc + r*16);
      vB[r] = *reinterpret_cast<const bf16x8*>(vsrc + r*16 + N1_);
    }

    for (int kt = 0; kt < nkt; kt++) {
      int kb = kt * 64;
      bool last = (kt == nkt - 1);

      // ---- wait K(t) landed (V(t) reg-loads may stay in flight) ----
      asm volatile("s_waitcnt vmcnt(8)" ::: "memory");

      // ---- QK^T: st[ks] = S^T (rows=keys, cols=queries) ----
      f32x16 st[2];
#pragma unroll
      for (int ks = 0; ks < 2; ks++) {
        f32x16 z = {};
#pragma unroll
        for (int kk = 0; kk < 4; kk++) {
          bf16x8 kf = *reinterpret_cast<const bf16x8*>(
              &Ks[(32*ks + q31)*64 + ((((kk<<1) | hi) ^ (q31 & 7)) << 3)]);
          z = __builtin_amdgcn_mfma_f32_32x32x16_bf16(kf, qf[kk], z, 0, 0, 0);
        }
        st[ks] = z;
      }
      asm volatile("s_waitcnt lgkmcnt(0)" ::: "memory");   // Ks reads retired
      __builtin_amdgcn_sched_barrier(0);

      // ---- prefetch K(t+1) into Ks (safe: QK reads drained) ----
      if (!last) {
        size_t off = (size_t)(kb + 64) * N1_;
#pragma unroll
        for (int r = 0; r < 8; r++)
          gload_lds16(ksrc + off + (size_t)(8*r) * N1_, (char*)Ks + r*1024);
      }

      // ---- online softmax (exp2 domain, lane-local q); mask only last tile ----
      float tmax = -__builtin_inff();
      if (last) {
#pragma unroll
        for (int ks = 0; ks < 2; ks++)
#pragma unroll
          for (int r = 0; r < 16; r++) {
            int keyg = kb + 32*ks + (r&3) + 8*(r>>2) + 4*hi;
            float s = (keyg > qg) ? -__builtin_inff() : st[ks][r];
            st[ks][r] = s;
            tmax = fmaxf(tmax, s);
          }
      } else {
#pragma unroll
        for (int ks = 0; ks < 2; ks++)
#pragma unroll
          for (int r = 0; r < 16; r++) tmax = fmaxf(tmax, st[ks][r]);
      }
      tmax = fmaxf(tmax, __shfl_xor(tmax, 32));
      if (!__all(tmax <= m_run + 8.f)) {
        float mnew = fmaxf(m_run, tmax);
        float rs = exp2f(m_run - mnew);
        l_run *= rs;
        m_run = mnew;
#pragma unroll
        for (int dt = 0; dt < 2; dt++)
#pragma unroll
          for (int r = 0; r < 16; r++) oacc[dt][r] *= rs;
      }
      float tsum = 0.f;
#pragma unroll
      for (int ks = 0; ks < 2; ks++)
#pragma unroll
        for (int r = 0; r < 16; r++) {
          float pp = exp2f(st[ks][r] - m_run);
          st[ks][r] = pp;
          tsum += pp;
        }
      l_run += tsum + __shfl_xor(tsum, 32);

      // ---- P pack + half-wave exchange -> pf[kc] (B-frags, keys 16kc+8hi+j) ----
      bf16x8 pf[4];
#pragma unroll
      for (int ks = 0; ks < 2; ks++) {
        u32 pk[8], rc[8];
#pragma unroll
        for (int m = 0; m < 8; m++)
          pk[m] = (u32)f2bf(st[ks][2*m]) | ((u32)f2bf(st[ks][2*m+1]) << 16);
#pragma unroll
        for (int m = 0; m < 8; m++)
          rc[m] = (u32)__shfl_xor((int)pk[m], 32);
        u32x4 fr0 = { hi ? rc[2] : pk[0], hi ? rc[3] : pk[1], hi ? pk[2] : rc[0], hi ? pk[3] : rc[1] };
        u32x4 fr1 = { hi ? rc[6] : pk[4], hi ? rc[7] : pk[5], hi ? pk[6] : rc[4], hi ? pk[7] : rc[5] };
        pf[2*ks]   = __builtin_bit_cast(bf16x8, fr0);
        pf[2*ks+1] = __builtin_bit_cast(bf16x8, fr1);
      }

      // ---- wait V(t) reg-loads ready (K(t+1) may remain in flight) ----
      if (!last) asm volatile("s_waitcnt vmcnt(8)" ::: "memory");
      else       asm volatile("s_waitcnt vmcnt(0)" ::: "memory");

      // ---- transpose-write V(t) into Vt (packed b32, swizzled; R6-proven) ----
#pragma unroll
      for (int r = 0; r < 4; r++) {
        const u16* au = (const u16*)&vA[r];
        const u16* bu = (const u16*)&vB[r];
#pragma unroll
        for (int i = 0; i < 8; i++) {
          int d = (hi + 2*r)*8 + i;
          Vt32[d*32 + (((kp>>2) ^ (d&7)) << 2) + (kp&3)] = (u32)au[i] | ((u32)bu[i] << 16);
        }
      }

      // ---- issue V(t+1) reg-loads (latency hidden under PV + next QK) ----
      if (!last) {
        size_t off = (size_t)(kb + 64) * N1_;
#pragma unroll
        for (int r = 0; r < 4; r++) {
          vA[r] = *reinterpret_cast<const bf16x8*>(vsrc + off + r*16);
          vB[r] = *reinterpret_cast<const bf16x8*>(vsrc + off + r*16 + N1_);
        }
      }

      // ---- PV: O^T += V^T * P^T (compiler handles write->read lgkm deps) ----
#pragma unroll
      for (int dt = 0; dt < 2; dt++)
#pragma unroll
        for (int kc = 0; kc < 4; kc++) {
          int c = (kc << 1) | hi;
          bf16x8 vf = *reinterpret_cast<const bf16x8*>(
              &Vt[(32*dt + q31)*64 + ((c ^ (q31 & 7)) << 3)]);
          oacc[dt] = __builtin_amdgcn_mfma_f32_32x32x16_bf16(vf, pf[kc], oacc[dt], 0, 0, 0);
        }
    }

    // ---- epilogue: divide by l (lane-local), write O (row q = qg) ----
    float linv = 1.f / l_run;
    u16* orow = attnout + (size_t)(b*T_ + qg) * C_ + h*HD_;
#pragma unroll
    for (int dt = 0; dt < 2; dt++)
#pragma unroll
      for (int m = 0; m < 8; m++) {
        int d = 32*dt + 2*(m&1) + 8*(m>>1) + 4*hi;
        u32 v = (u32)f2bf(oacc[dt][2*m] * linv) | ((u32)f2bf(oacc[dt][2*m+1] * linv) << 16);
        *reinterpret_cast<u32*>(orow + d) = v;
      }
  }
}

extern "C" void kernel_launch(void* const* d_in, const int* in_sizes, int n_in,
                              void* d_out, int out_size, void* d_ws, size_t ws_size,
                              hipStream_t stream) {
  const float* x     = (const float*)d_in[0];
  const float* w_qkv = (const float*)d_in[1];
  const float* w_out = (const float*)d_in[2];
  float* out = (float*)d_out;
  char* ws = (char*)d_ws;
  u16* xb    = (u16*)(ws);                         // 8 MB  : x bf16 (4096 x 1024)
  u16* wqkvT = (u16*)(ws + ((size_t)8  << 20));    // 6 MB  : w_qkv^T bf16 (3072 x 1024)
  u16* woutT = (u16*)(ws + ((size_t)14 << 20));    // 2 MB  : w_out^T bf16 (1024 x 1024)
  u16* qkvb  = (u16*)(ws + ((size_t)16 << 20));    // 24 MB : qkv bf16 (4096 x 3072)
  u16* attnb = (u16*)(ws + ((size_t)40 << 20));    // 8 MB  : attn out bf16 (4096 x 1024)

  cast_f32_bf16_k<<<(BT_*C_)/1024, 256, 0, stream>>>(x, xb, BT_*C_);
  transcast_k<<<dim3(N1_/32, C_/32), dim3(32, 8), 0, stream>>>(w_qkv, wqkvT, C_, N1_);
  transcast_k<<<dim3(C_/32, C_/32), dim3(32, 8), 0, stream>>>(w_out, woutT, C_, C_);
  gemm_bt<0><<<dim3(N1_/128, BT_/128), 256, 0, stream>>>(xb, wqkvT, (void*)qkvb, BT_, N1_, C_);
  attn_kernel<<<1024, 64, 0, stream>>>(qkvb, attnb);
  gemm_bt<1><<<dim3(C_/128, BT_/128), 256, 0, stream>>>(attnb, woutT, (void*)out, BT_, C_, C_);
}

// Round 10
// 141.149 us; speedup vs baseline: 1.2248x; 1.1845x over previous
//
#include <hip/hip_runtime.h>
#include <hip/hip_bf16.h>
#include <stdint.h>
#include <math.h>

#define B_ 2
#define T_ 2048
#define C_ 1024
#define H_ 16
#define HD_ 64
#define BT_ (B_*T_)      // 4096 rows
#define N1_ (3*C_)       // 3072

typedef unsigned short u16;
typedef uint32_t u32;
typedef __attribute__((ext_vector_type(8))) short bf16x8;
typedef __attribute__((ext_vector_type(4))) float f32x4;
typedef __attribute__((ext_vector_type(16))) float f32x16;
typedef __attribute__((ext_vector_type(4))) unsigned int u32x4;

__device__ __forceinline__ u16 f2bf(float f) {
  __hip_bfloat16 h = __float2bfloat16(f);
  return *reinterpret_cast<u16*>(&h);
}
__device__ __forceinline__ float bf2f(u16 u) {
  u32 w = ((u32)u) << 16;
  return *reinterpret_cast<float*>(&w);
}

__device__ __forceinline__ void gload_lds16(const void* g, void* l) {
  __builtin_amdgcn_global_load_lds(
      (const __attribute__((address_space(1))) uint32_t*)g,
      (__attribute__((address_space(3))) uint32_t*)l, 16, 0, 0);
}

// ---------------- cast x: fp32 -> bf16 ----------------
__global__ void cast_f32_bf16_k(const float* __restrict__ in, u16* __restrict__ out, int n) {
  int idx = (blockIdx.x * blockDim.x + threadIdx.x) * 4;
  if (idx >= n) return;
  float4 v = *reinterpret_cast<const float4*>(in + idx);
  u16 tmp[4] = {f2bf(v.x), f2bf(v.y), f2bf(v.z), f2bf(v.w)};
  *reinterpret_cast<uint2*>(out + idx) = *reinterpret_cast<const uint2*>(tmp);
}

// ---------------- transpose+cast: w (K x N fp32) -> wt (N x K bf16) ----------------
__global__ void transcast_k(const float* __restrict__ w, u16* __restrict__ wt, int K, int N) {
  __shared__ float tile[32][33];
  int n0 = blockIdx.x * 32, k0 = blockIdx.y * 32;
  int tx = threadIdx.x, ty = threadIdx.y;   // block (32,8)
#pragma unroll
  for (int i = 0; i < 4; i++)
    tile[ty + i*8][tx] = w[(size_t)(k0 + ty + i*8) * N + n0 + tx];
  __syncthreads();
#pragma unroll
  for (int i = 0; i < 4; i++)
    wt[(size_t)(n0 + ty + i*8) * K + k0 + tx] = f2bf(tile[tx][ty + i*8]);
}

// ---------------- GEMM: A (M x K bf16), Bt (N x K bf16) -> C (M x N) ----------------
template<int OUTF32>
__global__ __launch_bounds__(256) void gemm_bt(const u16* __restrict__ A, const u16* __restrict__ Bt,
                                               void* __restrict__ Cv, int M, int N, int K) {
  __shared__ u16 As[128*32];
  __shared__ u16 Bs[128*32];
  int tid = threadIdx.x, wave = tid >> 6, lane = tid & 63;
  int m0 = blockIdx.y * 128, n0 = blockIdx.x * 128;
  int wm = (wave >> 1) * 64, wn = (wave & 1) * 64;
  f32x4 acc[4][4] = {};
  int srow = lane >> 2, scol = (lane & 3) * 8;
  int fro  = (lane & 15) * 32 + (lane >> 4) * 8;

  for (int k0 = 0; k0 < K; k0 += 32) {
    __syncthreads();
#pragma unroll
    for (int i = 0; i < 2; i++) {
      gload_lds16(A  + (size_t)(m0 + i*64 + wave*16 + srow) * K + k0 + scol, &As[(i*64 + wave*16) * 32]);
      gload_lds16(Bt + (size_t)(n0 + i*64 + wave*16 + srow) * K + k0 + scol, &Bs[(i*64 + wave*16) * 32]);
    }
    asm volatile("s_waitcnt vmcnt(0)" ::: "memory");
    __syncthreads();
    bf16x8 af[4], bfr[4];
#pragma unroll
    for (int i = 0; i < 4; i++) af[i]  = *reinterpret_cast<const bf16x8*>(&As[(wm + i*16)*32 + fro]);
#pragma unroll
    for (int j = 0; j < 4; j++) bfr[j] = *reinterpret_cast<const bf16x8*>(&Bs[(wn + j*16)*32 + fro]);
#pragma unroll
    for (int i = 0; i < 4; i++)
#pragma unroll
      for (int j = 0; j < 4; j++)
        acc[i][j] = __builtin_amdgcn_mfma_f32_16x16x32_bf16(af[i], bfr[j], acc[i][j], 0, 0, 0);
  }
  int rg = (lane >> 4) * 4, cq = lane & 15;
#pragma unroll
  for (int i = 0; i < 4; i++)
#pragma unroll
    for (int j = 0; j < 4; j++) {
      size_t basei = (size_t)(m0 + wm + i*16 + rg) * N + (size_t)(n0 + wn + j*16 + cq);
#pragma unroll
      for (int r = 0; r < 4; r++) {
        if constexpr (OUTF32) ((float*)Cv)[basei + (size_t)r * N] = acc[i][j][r];
        else                  ((u16*)Cv)[basei + (size_t)r * N]   = f2bf(acc[i][j][r]);
      }
    }
}

// ---------------- causal flash attention: 2 waves / block, key-split ----------------
// 1024 blocks x 128 threads (8 waves/CU = 2/SIMD). xcd = lid&7 (HW round-robin,
// R6-proven): 4 heads per XCD -> 2MB K/V L2-resident. Each block owns strip pair
// {63-p, p} (33 tiles, constant). Within a strip, wave w handles tiles kt=w,w+2,...
// (online softmax is order-independent); partials merged in LDS at strip end.
// Per-tile body: R8/R9-proven counted-vmcnt pipeline, all waits per-wave.
__global__ __launch_bounds__(128) void attn_kernel(const u16* __restrict__ qkv, u16* __restrict__ attnout) {
  __shared__ u16 KsA[2][4096];   // per-wave K tile (8KB); KsA[1] reused as merge O-buffer
  __shared__ u16 VtA[2][4096];   // per-wave V^T tile; VtA[1] head reused for merge m,l
  int tid = threadIdx.x;
  int w = tid >> 6;              // wave id in block
  int lane = tid & 63;
  int q31 = lane & 31, hi = lane >> 5;
  int lid = blockIdx.x;
  int xcd = lid & 7, j = lid >> 3;
  int bh = xcd * 4 + (j & 3);    // 4 heads per XCD (L2 locality)
  int p = j >> 2;                // pair index 0..31 -> strips {63-p, p}
  int b = bh >> 4, h = bh & 15;
  const u16* base = qkv + (size_t)b * T_ * N1_;

  u16* Ks = KsA[w];
  u16* Vt = VtA[w];
  u32* Vt32 = reinterpret_cast<u32*>(Vt);

  // K staging source (pre-swizzled): key = 8r + (lane>>3), slot = lane&7 -> c = slot ^ (key&7)
  const u16* ksrc = base + C_ + h*HD_ + (size_t)(lane >> 3) * N1_
                    + (size_t)(((lane & 7) ^ ((lane >> 3) & 7)) * 8);
  // V staging: lane covers keys (2kp, 2kp+1) x d-chunks (hi + 2r)*8
  int kp = q31;
  const u16* vsrc = base + 2*C_ + h*HD_ + (size_t)(2*kp) * N1_ + hi*8;
  const float QSC = 0.125f * 1.44269504088896f;

  for (int sp = 0; sp < 2; sp++) {
    int strip = sp ? p : (63 - p);
    int qbase = strip * 32;
    int qg = qbase + q31;

    // Q fragments pre-scaled by 0.125*log2(e) (both waves load same rows)
    bf16x8 qf[4];
    {
      const u16* qrow = base + (size_t)qg * N1_ + h * HD_;
#pragma unroll
      for (int kk = 0; kk < 4; kk++) {
        bf16x8 raw = *reinterpret_cast<const bf16x8*>(qrow + kk*16 + hi*8);
        const u16* rp = (const u16*)&raw;
        u32x4 qp;
#pragma unroll
        for (int jj = 0; jj < 4; jj++)
          qp[jj] = (u32)f2bf(bf2f(rp[2*jj]) * QSC) | ((u32)f2bf(bf2f(rp[2*jj+1]) * QSC) << 16);
        qf[kk] = __builtin_bit_cast(bf16x8, qp);
      }
    }

    f32x16 oacc[2] = {};         // O^T partial: row d = (reg&3)+8(reg>>2)+4hi (+32dt)
    float m_run = -__builtin_inff(), l_run = 0.f;
    int nkt = (qbase >> 6) + 1;  // 64-key tiles this strip needs
    bool has = (w < nkt);

    if (has) {
      bf16x8 vA[4], vB[4];
      // ---- prologue: stage own first tile kt=w ----
      {
        size_t off0 = (size_t)(w * 64) * N1_;
#pragma unroll
        for (int r = 0; r < 8; r++)
          gload_lds16(ksrc + off0 + (size_t)(8*r) * N1_, (char*)Ks + r*1024);
#pragma unroll
        for (int r = 0; r < 4; r++) {
          vA[r] = *reinterpret_cast<const bf16x8*>(vsrc + off0 + r*16);
          vB[r] = *reinterpret_cast<const bf16x8*>(vsrc + off0 + r*16 + N1_);
        }
      }

      for (int kt = w; kt < nkt; kt += 2) {
        int kb = kt * 64;
        bool lastown  = (kt + 2 >= nkt);
        bool masktile = (kt == nkt - 1);

        // ---- wait K(t) landed (V(t) reg-loads may stay in flight) ----
        asm volatile("s_waitcnt vmcnt(8)" ::: "memory");

        // ---- QK^T: st[ks] = S^T (rows=keys, cols=queries) ----
        f32x16 st[2];
#pragma unroll
        for (int ks = 0; ks < 2; ks++) {
          f32x16 z = {};
#pragma unroll
          for (int kk = 0; kk < 4; kk++) {
            bf16x8 kf = *reinterpret_cast<const bf16x8*>(
                &Ks[(32*ks + q31)*64 + ((((kk<<1) | hi) ^ (q31 & 7)) << 3)]);
            z = __builtin_amdgcn_mfma_f32_32x32x16_bf16(kf, qf[kk], z, 0, 0, 0);
          }
          st[ks] = z;
        }
        asm volatile("s_waitcnt lgkmcnt(0)" ::: "memory");   // Ks reads retired
        __builtin_amdgcn_sched_barrier(0);

        // ---- prefetch own next tile K(t+2) ----
        if (!lastown) {
          size_t off = (size_t)(kb + 128) * N1_;
#pragma unroll
          for (int r = 0; r < 8; r++)
            gload_lds16(ksrc + off + (size_t)(8*r) * N1_, (char*)Ks + r*1024);
        }

        // ---- online softmax (exp2 domain); mask only the strip's final tile ----
        float tmax = -__builtin_inff();
        if (masktile) {
#pragma unroll
          for (int ks = 0; ks < 2; ks++)
#pragma unroll
            for (int r = 0; r < 16; r++) {
              int keyg = kb + 32*ks + (r&3) + 8*(r>>2) + 4*hi;
              float s = (keyg > qg) ? -__builtin_inff() : st[ks][r];
              st[ks][r] = s;
              tmax = fmaxf(tmax, s);
            }
        } else {
#pragma unroll
          for (int ks = 0; ks < 2; ks++)
#pragma unroll
            for (int r = 0; r < 16; r++) tmax = fmaxf(tmax, st[ks][r]);
        }
        tmax = fmaxf(tmax, __shfl_xor(tmax, 32));
        if (!__all(tmax <= m_run + 8.f)) {
          float mnew = fmaxf(m_run, tmax);
          float rs = exp2f(m_run - mnew);
          l_run *= rs;
          m_run = mnew;
#pragma unroll
          for (int dt = 0; dt < 2; dt++)
#pragma unroll
            for (int r = 0; r < 16; r++) oacc[dt][r] *= rs;
        }
        float tsum = 0.f;
#pragma unroll
        for (int ks = 0; ks < 2; ks++)
#pragma unroll
          for (int r = 0; r < 16; r++) {
            float pp = exp2f(st[ks][r] - m_run);
            st[ks][r] = pp;
            tsum += pp;
          }
        l_run += tsum + __shfl_xor(tsum, 32);

        // ---- P pack + half-wave exchange -> pf[kc] ----
        bf16x8 pf[4];
#pragma unroll
        for (int ks = 0; ks < 2; ks++) {
          u32 pk[8], rc[8];
#pragma unroll
          for (int m = 0; m < 8; m++)
            pk[m] = (u32)f2bf(st[ks][2*m]) | ((u32)f2bf(st[ks][2*m+1]) << 16);
#pragma unroll
          for (int m = 0; m < 8; m++)
            rc[m] = (u32)__shfl_xor((int)pk[m], 32);
          u32x4 fr0 = { hi ? rc[2] : pk[0], hi ? rc[3] : pk[1], hi ? pk[2] : rc[0], hi ? pk[3] : rc[1] };
          u32x4 fr1 = { hi ? rc[6] : pk[4], hi ? rc[7] : pk[5], hi ? pk[6] : rc[4], hi ? pk[7] : rc[5] };
          pf[2*ks]   = __builtin_bit_cast(bf16x8, fr0);
          pf[2*ks+1] = __builtin_bit_cast(bf16x8, fr1);
        }

        // ---- wait V(t) reg-loads ready (K(t+2) may remain in flight) ----
        if (!lastown) asm volatile("s_waitcnt vmcnt(8)" ::: "memory");
        else          asm volatile("s_waitcnt vmcnt(0)" ::: "memory");

        // ---- transpose-write V(t) into Vt (packed b32, swizzled) ----
#pragma unroll
        for (int r = 0; r < 4; r++) {
          const u16* au = (const u16*)&vA[r];
          const u16* bu = (const u16*)&vB[r];
#pragma unroll
          for (int i = 0; i < 8; i++) {
            int d = (hi + 2*r)*8 + i;
            Vt32[d*32 + (((kp>>2) ^ (d&7)) << 2) + (kp&3)] = (u32)au[i] | ((u32)bu[i] << 16);
          }
        }

        // ---- issue own V(t+2) reg-loads ----
        if (!lastown) {
          size_t off = (size_t)(kb + 128) * N1_;
#pragma unroll
          for (int r = 0; r < 4; r++) {
            vA[r] = *reinterpret_cast<const bf16x8*>(vsrc + off + r*16);
            vB[r] = *reinterpret_cast<const bf16x8*>(vsrc + off + r*16 + N1_);
          }
        }

        // ---- PV: O^T += V^T * P^T ----
#pragma unroll
        for (int dt = 0; dt < 2; dt++)
#pragma unroll
          for (int kc = 0; kc < 4; kc++) {
            int c = (kc << 1) | hi;
            bf16x8 vf = *reinterpret_cast<const bf16x8*>(
                &Vt[(32*dt + q31)*64 + ((c ^ (q31 & 7)) << 3)]);
            oacc[dt] = __builtin_amdgcn_mfma_f32_32x32x16_bf16(vf, pf[kc], oacc[dt], 0, 0, 0);
          }
      }
    }

    // ---- merge partials across the two waves (flash combine) ----
    __syncthreads();
    if (w == 1) {
      float* ob = (float*)KsA[1];           // 2048 floats: [ (dt*16+r)*64 + lane ]
      float* ml = (float*)VtA[1];           // m at [lane], l at [64+lane]
#pragma unroll
      for (int dt = 0; dt < 2; dt++)
#pragma unroll
        for (int r = 0; r < 16; r++) ob[(dt*16 + r)*64 + lane] = oacc[dt][r];
      ml[lane] = m_run;
      ml[64 + lane] = l_run;
    }
    __syncthreads();
    if (w == 0) {
      const float* ob = (const float*)KsA[1];
      const float* ml = (const float*)VtA[1];
      float m1 = ml[lane], l1 = ml[64 + lane];
      float mC = fmaxf(m_run, m1);
      float w0s = exp2f(m_run - mC);
      float w1s = exp2f(m1 - mC);        // exp2(-inf)=0 handles empty wave-1 partials
      float linv = 1.f / (l_run * w0s + l1 * w1s);
      u16* orow = attnout + (size_t)(b*T_ + qg) * C_ + h*HD_;
#pragma unroll
      for (int dt = 0; dt < 2; dt++)
#pragma unroll
        for (int m = 0; m < 8; m++) {
          float v0 = (oacc[dt][2*m]   * w0s + ob[(dt*16 + 2*m)*64 + lane]   * w1s) * linv;
          float v1 = (oacc[dt][2*m+1] * w0s + ob[(dt*16 + 2*m+1)*64 + lane] * w1s) * linv;
          int d = 32*dt + 2*(m&1) + 8*(m>>1) + 4*hi;
          u32 v = (u32)f2bf(v0) | ((u32)f2bf(v1) << 16);
          *reinterpret_cast<u32*>(orow + d) = v;
        }
    }
    __syncthreads();
  }
}

extern "C" void kernel_launch(void* const* d_in, const int* in_sizes, int n_in,
                              void* d_out, int out_size, void* d_ws, size_t ws_size,
                              hipStream_t stream) {
  const float* x     = (const float*)d_in[0];
  const float* w_qkv = (const float*)d_in[1];
  const float* w_out = (const float*)d_in[2];
  float* out = (float*)d_out;
  char* ws = (char*)d_ws;
  u16* xb    = (u16*)(ws);                         // 8 MB  : x bf16 (4096 x 1024)
  u16* wqkvT = (u16*)(ws + ((size_t)8  << 20));    // 6 MB  : w_qkv^T bf16 (3072 x 1024)
  u16* woutT = (u16*)(ws + ((size_t)14 << 20));    // 2 MB  : w_out^T bf16 (1024 x 1024)
  u16* qkvb  = (u16*)(ws + ((size_t)16 << 20));    // 24 MB : qkv bf16 (4096 x 3072)
  u16* attnb = (u16*)(ws + ((size_t)40 << 20));    // 8 MB  : attn out bf16 (4096 x 1024)

  cast_f32_bf16_k<<<(BT_*C_)/1024, 256, 0, stream>>>(x, xb, BT_*C_);
  transcast_k<<<dim3(N1_/32, C_/32), dim3(32, 8), 0, stream>>>(w_qkv, wqkvT, C_, N1_);
  transcast_k<<<dim3(C_/32, C_/32), dim3(32, 8), 0, stream>>>(w_out, woutT, C_, C_);
  gemm_bt<0><<<dim3(N1_/128, BT_/128), 256, 0, stream>>>(xb, wqkvT, (void*)qkvb, BT_, N1_, C_);
  attn_kernel<<<1024, 128, 0, stream>>>(qkvb, attnb);
  gemm_bt<1><<<dim3(C_/128, BT_/128), 256, 0, stream>>>(attnb, woutT, (void*)out, BT_, C_, C_);
}

// Round 11
// 138.513 us; speedup vs baseline: 1.2482x; 1.0190x over previous
//
#include <hip/hip_runtime.h>
#include <hip/hip_bf16.h>
#include <stdint.h>
#include <math.h>

#define B_ 2
#define T_ 2048
#define C_ 1024
#define H_ 16
#define HD_ 64
#define BT_ (B_*T_)      // 4096 rows
#define N1_ (3*C_)       // 3072

typedef unsigned short u16;
typedef uint32_t u32;
typedef __attribute__((ext_vector_type(8))) short bf16x8;
typedef __attribute__((ext_vector_type(4))) float f32x4;
typedef __attribute__((ext_vector_type(16))) float f32x16;
typedef __attribute__((ext_vector_type(4))) unsigned int u32x4;

__device__ __forceinline__ u16 f2bf(float f) {
  __hip_bfloat16 h = __float2bfloat16(f);
  return *reinterpret_cast<u16*>(&h);
}
__device__ __forceinline__ float bf2f(u16 u) {
  u32 w = ((u32)u) << 16;
  return *reinterpret_cast<float*>(&w);
}
__device__ __forceinline__ u32 cvtpk(float lo, float hi) {
  u32 r;
  asm("v_cvt_pk_bf16_f32 %0, %1, %2" : "=v"(r) : "v"(lo), "v"(hi));
  return r;
}

__device__ __forceinline__ void gload_lds16(const void* g, void* l) {
  __builtin_amdgcn_global_load_lds(
      (const __attribute__((address_space(1))) uint32_t*)g,
      (__attribute__((address_space(3))) uint32_t*)l, 16, 0, 0);
}

// ---------------- cast x: fp32 -> bf16 ----------------
__global__ void cast_f32_bf16_k(const float* __restrict__ in, u16* __restrict__ out, int n) {
  int idx = (blockIdx.x * blockDim.x + threadIdx.x) * 4;
  if (idx >= n) return;
  float4 v = *reinterpret_cast<const float4*>(in + idx);
  u16 tmp[4] = {f2bf(v.x), f2bf(v.y), f2bf(v.z), f2bf(v.w)};
  *reinterpret_cast<uint2*>(out + idx) = *reinterpret_cast<const uint2*>(tmp);
}

// ---------------- transpose+cast: w (K x N fp32) -> wt (N x K bf16) ----------------
__global__ void transcast_k(const float* __restrict__ w, u16* __restrict__ wt, int K, int N) {
  __shared__ float tile[32][33];
  int n0 = blockIdx.x * 32, k0 = blockIdx.y * 32;
  int tx = threadIdx.x, ty = threadIdx.y;   // block (32,8)
#pragma unroll
  for (int i = 0; i < 4; i++)
    tile[ty + i*8][tx] = w[(size_t)(k0 + ty + i*8) * N + n0 + tx];
  __syncthreads();
#pragma unroll
  for (int i = 0; i < 4; i++)
    wt[(size_t)(n0 + ty + i*8) * K + k0 + tx] = f2bf(tile[tx][ty + i*8]);
}

// ---------------- GEMM: A (M x K bf16), Bt (N x K bf16) -> C (M x N) ----------------
template<int OUTF32>
__global__ __launch_bounds__(256) void gemm_bt(const u16* __restrict__ A, const u16* __restrict__ Bt,
                                               void* __restrict__ Cv, int M, int N, int K) {
  __shared__ u16 As[128*32];
  __shared__ u16 Bs[128*32];
  int tid = threadIdx.x, wave = tid >> 6, lane = tid & 63;
  int m0 = blockIdx.y * 128, n0 = blockIdx.x * 128;
  int wm = (wave >> 1) * 64, wn = (wave & 1) * 64;
  f32x4 acc[4][4] = {};
  int srow = lane >> 2, scol = (lane & 3) * 8;
  int fro  = (lane & 15) * 32 + (lane >> 4) * 8;

  for (int k0 = 0; k0 < K; k0 += 32) {
    __syncthreads();
#pragma unroll
    for (int i = 0; i < 2; i++) {
      gload_lds16(A  + (size_t)(m0 + i*64 + wave*16 + srow) * K + k0 + scol, &As[(i*64 + wave*16) * 32]);
      gload_lds16(Bt + (size_t)(n0 + i*64 + wave*16 + srow) * K + k0 + scol, &Bs[(i*64 + wave*16) * 32]);
    }
    asm volatile("s_waitcnt vmcnt(0)" ::: "memory");
    __syncthreads();
    bf16x8 af[4], bfr[4];
#pragma unroll
    for (int i = 0; i < 4; i++) af[i]  = *reinterpret_cast<const bf16x8*>(&As[(wm + i*16)*32 + fro]);
#pragma unroll
    for (int j = 0; j < 4; j++) bfr[j] = *reinterpret_cast<const bf16x8*>(&Bs[(wn + j*16)*32 + fro]);
#pragma unroll
    for (int i = 0; i < 4; i++)
#pragma unroll
      for (int j = 0; j < 4; j++)
        acc[i][j] = __builtin_amdgcn_mfma_f32_16x16x32_bf16(af[i], bfr[j], acc[i][j], 0, 0, 0);
  }
  int rg = (lane >> 4) * 4, cq = lane & 15;
#pragma unroll
  for (int i = 0; i < 4; i++)
#pragma unroll
    for (int j = 0; j < 4; j++) {
      size_t basei = (size_t)(m0 + wm + i*16 + rg) * N + (size_t)(n0 + wn + j*16 + cq);
#pragma unroll
      for (int r = 0; r < 4; r++) {
        if constexpr (OUTF32) ((float*)Cv)[basei + (size_t)r * N] = acc[i][j][r];
        else                  ((u16*)Cv)[basei + (size_t)r * N]   = f2bf(acc[i][j][r]);
      }
    }
}

// ---------------- causal flash attention: 4 waves / block, 4-way key-split ----------------
// 1024 blocks x 256 threads = 4096 waves = 4/SIMD (LDS 32KB -> 4 blocks/CU; VGPR<=128).
// xcd = lid&7 (HW round-robin, R6-proven): 4 heads per XCD -> K/V L2-resident.
// Block owns strip pair {63-p, p} (65 32-key tiles, constant work). Wave w handles
// tiles kt = w, w+4, ... with PRIVATE 8KB K/V (no barriers in the loop); 4-way flash
// merge in LDS at strip end. Per-tile body = R10-proven structure at KVBLK=32 with
// counted-vmcnt (wait 4; 0 only on own last tile) + cvt_pk VALU diet.
__global__ __launch_bounds__(256, 4) void attn_kernel(const u16* __restrict__ qkv, u16* __restrict__ attnout) {
  __shared__ u16 Sm[4][4096];    // per wave: K tile [0..2047], V^T tile [2048..4095]
  int tid = threadIdx.x;
  int w = tid >> 6, lane = tid & 63;
  int q31 = lane & 31, hi = lane >> 5;
  int lid = blockIdx.x;
  int xcd = lid & 7, j = lid >> 3;
  int bh = xcd * 4 + (j & 3);
  int p = j >> 2;                // 0..31 -> strips {63-p, p}
  int b = bh >> 4, h = bh & 15;
  const u16* base = qkv + (size_t)b * T_ * N1_;

  u16* Ks = Sm[w];
  u32* Vt32 = reinterpret_cast<u32*>(Sm[w] + 2048);

  // K staging source (pre-swizzled, identical to R10): key = 8r+(lane>>3), slot = lane&7
  const u16* ksrc = base + C_ + h*HD_ + (size_t)(lane >> 3) * N1_
                    + (size_t)(((lane & 7) ^ ((lane >> 3) & 7)) * 8);
  // V staging: lane covers keys {2kp2, 2kp2+1} x d = dc..dc+15
  int kp2 = lane & 15, dc = (lane >> 4) * 16;
  int vcs = kp2 >> 2, vkl = kp2 & 3;
  const u16* vsrc = base + 2*C_ + h*HD_ + (size_t)(2*kp2) * N1_ + dc;
  const float QSC = 0.125f * 1.44269504088896f;
  int swr = (q31 >> 1) & 3;      // V read swizzle

  for (int sp = 0; sp < 2; sp++) {
    int strip = sp ? p : (63 - p);
    int qbase = strip * 32;
    int qg = qbase + q31;
    int nkt = strip + 1;         // 32-key tiles this strip needs

    f32x16 oacc[2] = {};         // O^T: row d = (reg&3)+8(reg>>2)+4hi (+32dt), col q31
    float m_run = -__builtin_inff(), l_run = 0.f;

    if (w < nkt) {
      // Q fragments pre-scaled into exp2 domain
      bf16x8 qf[4];
      {
        const u16* qrow = base + (size_t)qg * N1_ + h * HD_;
#pragma unroll
        for (int kk = 0; kk < 4; kk++) {
          bf16x8 raw = *reinterpret_cast<const bf16x8*>(qrow + kk*16 + hi*8);
          const u16* rp = (const u16*)&raw;
          u32x4 qp;
#pragma unroll
          for (int jj = 0; jj < 4; jj++)
            qp[jj] = cvtpk(bf2f(rp[2*jj]) * QSC, bf2f(rp[2*jj+1]) * QSC);
          qf[kk] = __builtin_bit_cast(bf16x8, qp);
        }
      }

      bf16x8 vA[2], vB[2];
      // ---- prologue: stage own first tile kt=w (K gloads then V reg-loads) ----
      {
        size_t off0 = (size_t)(w * 32) * N1_;
#pragma unroll
        for (int r = 0; r < 4; r++)
          gload_lds16(ksrc + off0 + (size_t)(8*r) * N1_, (char*)Ks + r*1024);
#pragma unroll
        for (int r = 0; r < 2; r++) {
          vA[r] = *reinterpret_cast<const bf16x8*>(vsrc + off0 + r*8);
          vB[r] = *reinterpret_cast<const bf16x8*>(vsrc + off0 + r*8 + N1_);
        }
      }

      for (int kt = w; kt < nkt; kt += 4) {
        int kb = kt * 32;
        bool lastown  = (kt + 4 >= nkt);
        bool masktile = (kt == nkt - 1);

        // ---- wait K(t) landed (V(t) reg-loads may stay in flight) ----
        asm volatile("s_waitcnt vmcnt(4)" ::: "memory");

        // ---- QK^T: st = S^T (32 keys x 32 q) ----
        f32x16 st = {};
#pragma unroll
        for (int kk = 0; kk < 4; kk++) {
          bf16x8 kf = *reinterpret_cast<const bf16x8*>(
              &Ks[q31*64 + ((((kk<<1) | hi) ^ (q31 & 7)) << 3)]);
          st = __builtin_amdgcn_mfma_f32_32x32x16_bf16(kf, qf[kk], st, 0, 0, 0);
        }
        asm volatile("s_waitcnt lgkmcnt(0)" ::: "memory");   // Ks reads retired
        __builtin_amdgcn_sched_barrier(0);

        // ---- prefetch own next K(t+4) ----
        if (!lastown) {
          size_t off = (size_t)(kb + 128) * N1_;
#pragma unroll
          for (int r = 0; r < 4; r++)
            gload_lds16(ksrc + off + (size_t)(8*r) * N1_, (char*)Ks + r*1024);
        }

        // ---- online softmax (exp2 domain); mask only the strip's final tile ----
        float tmax = -__builtin_inff();
        if (masktile) {
#pragma unroll
          for (int r = 0; r < 16; r++) {
            int keyg = kb + (r&3) + 8*(r>>2) + 4*hi;
            float s = (keyg > qg) ? -__builtin_inff() : st[r];
            st[r] = s;
            tmax = fmaxf(tmax, s);
          }
        } else {
#pragma unroll
          for (int r = 0; r < 16; r++) tmax = fmaxf(tmax, st[r]);
        }
        tmax = fmaxf(tmax, __shfl_xor(tmax, 32));
        if (!__all(tmax <= m_run + 8.f)) {
          float mnew = fmaxf(m_run, tmax);
          float rs = exp2f(m_run - mnew);
          l_run *= rs;
          m_run = mnew;
#pragma unroll
          for (int dt = 0; dt < 2; dt++)
#pragma unroll
            for (int r = 0; r < 16; r++) oacc[dt][r] *= rs;
        }
        float tsum = 0.f;
#pragma unroll
        for (int r = 0; r < 16; r++) {
          float pp = exp2f(st[r] - m_run);
          st[r] = pp;
          tsum += pp;
        }
        l_run += tsum + __shfl_xor(tsum, 32);

        // ---- P pack (cvt_pk) + half-wave exchange -> pf[kc] (keys 16kc+8hi+j) ----
        bf16x8 pf[2];
        {
          u32 pk[8], rc[8];
#pragma unroll
          for (int m = 0; m < 8; m++) pk[m] = cvtpk(st[2*m], st[2*m+1]);
#pragma unroll
          for (int m = 0; m < 8; m++) rc[m] = (u32)__shfl_xor((int)pk[m], 32);
          u32x4 fr0 = { hi ? rc[2] : pk[0], hi ? rc[3] : pk[1], hi ? pk[2] : rc[0], hi ? pk[3] : rc[1] };
          u32x4 fr1 = { hi ? rc[6] : pk[4], hi ? rc[7] : pk[5], hi ? pk[6] : rc[4], hi ? pk[7] : rc[5] };
          pf[0] = __builtin_bit_cast(bf16x8, fr0);
          pf[1] = __builtin_bit_cast(bf16x8, fr1);
        }

        // ---- wait V(t) reg-loads ready (K(t+4) may remain in flight) ----
        if (!lastown) asm volatile("s_waitcnt vmcnt(4)" ::: "memory");
        else          asm volatile("s_waitcnt vmcnt(0)" ::: "memory");

        // ---- transpose-write V(t): 16 packed b32, swizzle slot=(key>>3)^((d>>1)&3) ----
#pragma unroll
        for (int r2 = 0; r2 < 2; r2++) {
          const u16* au = (const u16*)&vA[r2];
          const u16* bu = (const u16*)&vB[r2];
#pragma unroll
          for (int i = 0; i < 8; i++) {
            int d = dc + r2*8 + i;
            Vt32[d*16 + ((vcs ^ ((d>>1)&3)) << 2) + vkl] = (u32)au[i] | ((u32)bu[i] << 16);
          }
        }

        // ---- issue own V(t+4) reg-loads ----
        if (!lastown) {
          size_t off = (size_t)(kb + 128) * N1_;
#pragma unroll
          for (int r = 0; r < 2; r++) {
            vA[r] = *reinterpret_cast<const bf16x8*>(vsrc + off + r*8);
            vB[r] = *reinterpret_cast<const bf16x8*>(vsrc + off + r*8 + N1_);
          }
        }

        // ---- PV: O^T += V^T * P^T ----
#pragma unroll
        for (int dt = 0; dt < 2; dt++)
#pragma unroll
          for (int kc = 0; kc < 2; kc++) {
            int cs = (kc << 1) | hi;
            bf16x8 vf = *reinterpret_cast<const bf16x8*>(
                &Vt32[(32*dt + q31)*16 + ((cs ^ swr) << 2)]);
            oacc[dt] = __builtin_amdgcn_mfma_f32_32x32x16_bf16(vf, pf[kc], oacc[dt], 0, 0, 0);
          }
      }
    }

    // ---- 4-way flash merge ----
    __syncthreads();
    if (w) {
      float* park = (float*)Sm[w];
#pragma unroll
      for (int dt = 0; dt < 2; dt++)
#pragma unroll
        for (int r = 0; r < 16; r++) park[(dt*16 + r)*64 + lane] = oacc[dt][r];
      float* ml = (float*)Sm[0];
      ml[(w-1)*128 + lane] = m_run;
      ml[(w-1)*128 + 64 + lane] = l_run;
    }
    __syncthreads();
    if (w == 0) {
      const float* ml = (const float*)Sm[0];
      float m1 = ml[lane],       l1 = ml[64 + lane];
      float m2 = ml[128 + lane], l2 = ml[192 + lane];
      float m3 = ml[256 + lane], l3 = ml[320 + lane];
      float mC = fmaxf(fmaxf(m_run, m1), fmaxf(m2, m3));
      float w0 = exp2f(m_run - mC), w1 = exp2f(m1 - mC);
      float w2 = exp2f(m2 - mC),    w3 = exp2f(m3 - mC);
      float linv = 1.f / (l_run*w0 + l1*w1 + l2*w2 + l3*w3);
      const float* p1 = (const float*)Sm[1];
      const float* p2 = (const float*)Sm[2];
      const float* p3 = (const float*)Sm[3];
      u16* orow = attnout + (size_t)(b*T_ + qg) * C_ + h*HD_;
#pragma unroll
      for (int dt = 0; dt < 2; dt++)
#pragma unroll
        for (int m = 0; m < 8; m++) {
          int e0 = (dt*16 + 2*m)*64 + lane, e1 = e0 + 64;
          float v0 = (oacc[dt][2*m]   * w0 + p1[e0]*w1 + p2[e0]*w2 + p3[e0]*w3) * linv;
          float v1 = (oacc[dt][2*m+1] * w0 + p1[e1]*w1 + p2[e1]*w2 + p3[e1]*w3) * linv;
          int d = 32*dt + 2*(m&1) + 8*(m>>1) + 4*hi;
          *reinterpret_cast<u32*>(orow + d) = cvtpk(v0, v1);
        }
    }
    __syncthreads();
  }
}

extern "C" void kernel_launch(void* const* d_in, const int* in_sizes, int n_in,
                              void* d_out, int out_size, void* d_ws, size_t ws_size,
                              hipStream_t stream) {
  const float* x     = (const float*)d_in[0];
  const float* w_qkv = (const float*)d_in[1];
  const float* w_out = (const float*)d_in[2];
  float* out = (float*)d_out;
  char* ws = (char*)d_ws;
  u16* xb    = (u16*)(ws);                         // 8 MB  : x bf16 (4096 x 1024)
  u16* wqkvT = (u16*)(ws + ((size_t)8  << 20));    // 6 MB  : w_qkv^T bf16 (3072 x 1024)
  u16* woutT = (u16*)(ws + ((size_t)14 << 20));    // 2 MB  : w_out^T bf16 (1024 x 1024)
  u16* qkvb  = (u16*)(ws + ((size_t)16 << 20));    // 24 MB : qkv bf16 (4096 x 3072)
  u16* attnb = (u16*)(ws + ((size_t)40 << 20));    // 8 MB  : attn out bf16 (4096 x 1024)

  cast_f32_bf16_k<<<(BT_*C_)/1024, 256, 0, stream>>>(x, xb, BT_*C_);
  transcast_k<<<dim3(N1_/32, C_/32), dim3(32, 8), 0, stream>>>(w_qkv, wqkvT, C_, N1_);
  transcast_k<<<dim3(C_/32, C_/32), dim3(32, 8), 0, stream>>>(w_out, woutT, C_, C_);
  gemm_bt<0><<<dim3(N1_/128, BT_/128), 256, 0, stream>>>(xb, wqkvT, (void*)qkvb, BT_, N1_, C_);
  attn_kernel<<<1024, 256, 0, stream>>>(qkvb, attnb);
  gemm_bt<1><<<dim3(C_/128, BT_/128), 256, 0, stream>>>(attnb, woutT, (void*)out, BT_, C_, C_);
}